// Round 16
// baseline (666.443 us; speedup 1.0000x reference)
//
#include <hip/hip_runtime.h>
#include <math.h>

// LIF_13984413516471 — exact serial chain with GROUP-level (64-t, 512-substep)
// staircase skip: spiking groups collapse to one readlane; quiet groups run
// certified pure adds; uncertain run exact STEP8. Window-entry states for the
// output pass are reconstructed by a parallel exact replay kernel.
// B=128, S=128, H=128, K=8. Reference: one scalar accumulator per batch,
// sequential over (i,j,k); per substep: s += x; if (s > th[k]) s = 0.
// Outputs (B,S,K,H) fp32: outs | spikes. Bitwise-exact fp32 replay.
//
// Staircase over a group (validated at window level in R14/R15, absmax 0.0):
// before any spike the fp32 chain equals entry s + pure prefix; first-spike
// index tau(s) is monotone in s with breakpoints = running-min records of
// m_j = th_k(j) - P_j (f64). Certified skip at record i requires
// s > v_i + mg and s < v_{i-1} - mg; then |s| <= 1 + maxAbsP (bracketed by
// record values), total fp32 drift over <=512 adds <= 3.2e-5*(2*maxAbsP+2),
// covered by mg -> fp32 chain provably first-spikes at j_i, resets to 0,
// exit = exact data-only continuation K_i (computed exactly in fp32).
// Certified quiet (slot-15 catch-all): s <= rmin - m15 with m15 covering
// drift for |s| <= 65536 (64 sigma of the entire walk) -> pure adds are
// bitwise-exact. Everything else: exact STEP8 redo.

#define NB 128
#define NS 128
#define NH 128
#define NK 8
#define NT (NS * NH)            // 16384 t per batch
#define NW2 (NT / 8)            // 2048 windows per batch
#define NG64 (NT / 64)          // 256 groups (64 t = 512 substeps each)
#define OUTN ((size_t)NB * NS * NK * NH)

// ---- ws layout (floats) ----
#define WS_SENT2 0                              // group entries [NB][NG64]
#define WS_SENT  (NB * NG64)                    // window entries [NB][NW2]
#define WS_HI    (WS_SENT + NB * NW2)           // HI [NB][NG64][16]
#define WS_LO    (WS_HI + NB * NG64 * 16)       // LO [NB][NG64][16]
#define WS_PK    (WS_LO + NB * NG64 * 16)       // K  [NB][NG64][16]
#define WS_JT    (WS_PK + NB * NG64 * 16)       // J  [NB][NG64][16] (int)
#define WS_TOT   (WS_JT + NB * NG64 * 16)       // ~9.6 MB

__device__ __forceinline__ float rl(float v, int idx) {
    return __int_as_float(__builtin_amdgcn_readlane(__float_as_int(v), idx));
}

#define ADD8(xv) do { s += xv; s += xv; s += xv; s += xv; \
                      s += xv; s += xv; s += xv; s += xv; } while (0)
#define STEP8(xv) do { \
    s += xv; s = (s > th0) ? 0.0f : s; \
    s += xv; s = (s > th1) ? 0.0f : s; \
    s += xv; s = (s > th2) ? 0.0f : s; \
    s += xv; s = (s > th3) ? 0.0f : s; \
    s += xv; s = (s > th4) ? 0.0f : s; \
    s += xv; s = (s > th5) ? 0.0f : s; \
    s += xv; s = (s > th6) ? 0.0f : s; \
    s += xv; s = (s > th7) ? 0.0f : s; } while (0)

// ---- records: one thread per group, scratch-free named slots ----
#define RSLOT(i) \
    v##i = (rec && nr == i) ? m : v##i; \
    j##i = (rec && nr == i) ? ss : j##i;

__global__ void __launch_bounds__(256)
lif_rec(const float* __restrict__ x, const float* __restrict__ th,
        float* __restrict__ HI, float* __restrict__ LO, int* __restrict__ JT)
{
    int idx = blockIdx.x * 256 + threadIdx.x;   // b*NG64 + gg
    if (idx >= NB * NG64) return;
    int b = idx >> 8, gg = idx & (NG64 - 1);
    const float* xg = x + (size_t)b * NT + gg * 64;
    const float t0 = th[0], t1 = th[1], t2 = th[2], t3 = th[3];
    const float t4 = th[4], t5 = th[5], t6 = th[6], t7 = th[7];

    double p = 0.0, rmin = 1e300, map = 0.0;
    double v0 = 0, v1 = 0, v2 = 0, v3 = 0, v4 = 0, v5 = 0, v6 = 0, v7 = 0;
    double v8 = 0, v9 = 0, v10 = 0, v11 = 0, v12 = 0, v13 = 0, v14 = 0;
    int j0 = 512, j1 = 512, j2 = 512, j3 = 512, j4 = 512, j5 = 512, j6 = 512;
    int j7 = 512, j8 = 512, j9 = 512, j10 = 512, j11 = 512, j12 = 512;
    int j13 = 512, j14 = 512;
    int nr = 0;

    for (int ti = 0; ti < 64; ++ti) {
        double xv = (double)xg[ti];
#pragma unroll
        for (int k = 0; k < 8; ++k) {
            p += xv;
            map = fmax(map, fabs(p));
            double tk = (k == 0) ? t0 : (k == 1) ? t1 : (k == 2) ? t2 :
                        (k == 3) ? t3 : (k == 4) ? t4 : (k == 5) ? t5 :
                        (k == 6) ? t6 : t7;
            double m = tk - p;
            bool rec = m < rmin;
            rmin = rec ? m : rmin;
            const int ss = ti * 8 + k;
            RSLOT(0) RSLOT(1) RSLOT(2) RSLOT(3) RSLOT(4)
            RSLOT(5) RSLOT(6) RSLOT(7) RSLOT(8) RSLOT(9)
            RSLOT(10) RSLOT(11) RSLOT(12) RSLOT(13) RSLOT(14)
            nr = rec ? nr + 1 : nr;
        }
    }

    const double mg  = 3.2e-5 * (2.0 * map + 2.0) + 1e-3;
    const double m15 = 3.2e-5 * (map + 65536.0) + 1e-3;
    size_t base = (size_t)idx * 16;
#define STSLOT(i) { bool val = (j##i < 512); \
    HI[base + i] = val ? (float)(v##i + mg) : 3.0e38f; \
    LO[base + i] = val ? (float)(v##i - mg) : 3.0e38f; \
    JT[base + i] = j##i; }
    STSLOT(0) STSLOT(1) STSLOT(2) STSLOT(3) STSLOT(4)
    STSLOT(5) STSLOT(6) STSLOT(7) STSLOT(8) STSLOT(9)
    STSLOT(10) STSLOT(11) STSLOT(12) STSLOT(13) STSLOT(14)
#undef STSLOT
    HI[base + 15] = 3.0e38f;                    // catch-all: never a skip
    LO[base + 15] = (float)(rmin - m15);        // true quiet bound
    JT[base + 15] = 512;
}

// ---- continuations: one thread per (group, slot); exact fp32 from reset ----
__global__ void __launch_bounds__(256)
lif_cont(const float* __restrict__ x, const float* __restrict__ th,
         const int* __restrict__ JT, float* __restrict__ PK)
{
    int idx = blockIdx.x * 256 + threadIdx.x;   // b*4096 + gg*16 + slot
    if (idx >= NB * NG64 * 16) return;
    int b = idx >> 12;
    int r = idx & 4095;
    int gg = r >> 4;
    int j = JT[idx];
    float out = 0.0f;
    if (j < 512) {
        const float* xg = x + (size_t)b * NT + gg * 64;
        const float th0 = th[0], th1 = th[1], th2 = th[2], th3 = th[3];
        const float th4 = th[4], th5 = th[5], th6 = th[6], th7 = th[7];
        int jt = j >> 3, jk = j & 7;
        float s = 0.0f;
        {   // partial first t (substeps j+1 .. jt*8+7), compile-time k
            float xv = xg[jt];
#pragma unroll
            for (int k = 0; k < 8; ++k) {
                float tk = (k == 0) ? th0 : (k == 1) ? th1 : (k == 2) ? th2 :
                           (k == 3) ? th3 : (k == 4) ? th4 : (k == 5) ? th5 :
                           (k == 6) ? th6 : th7;
                float ns = s + xv;
                ns = (ns > tk) ? 0.0f : ns;
                s = (k > jk) ? ns : s;
            }
        }
        for (int ti = jt + 1; ti < 64; ++ti) {
            float xv = xg[ti];
            STEP8(xv);
        }
        out = s;
    }
    PK[idx] = out;
}

// ---- chain: 1 batch per wave; group-level skip/quiet/redo ----
#define PROCESS(cH, cL, cK, cx, ggexpr) do { \
    const int _gg = (ggexpr); \
    keep = (lane == (_gg & 63)) ? s : keep; \
    unsigned long long _bH = __ballot(s > (cH)); \
    unsigned long long _bL = __ballot(s > (cL)); \
    unsigned _hi = (unsigned)_bH & 0xffffu; \
    unsigned _lo = (unsigned)_bL & 0xffffu; \
    int _ii = __ffs((int)_hi); \
    unsigned _below = _ii ? (_lo & ((1u << (_ii - 1)) - 1u)) : _lo; \
    int _cls = (_ii && _below == 0u) ? 1 : ((_lo == 0u) ? 2 : 0); \
    _cls = __builtin_amdgcn_readfirstlane(_cls); \
    if (_cls == 1) { \
        s = rl((cK), _ii - 1);            /* certified: whole group skipped */ \
    } else if (_cls == 2) { \
        for (int _w = 0; _w < 8; ++_w) {  /* certified quiet: pure adds */ \
            _Pragma("unroll") \
            for (int _m = 0; _m < 8; ++_m) { \
                float _xc = rl((cx), _w * 8 + _m); \
                ADD8(_xc); \
            } \
        } \
    } else { \
        for (int _w = 0; _w < 8; ++_w) {  /* uncertain: exact redo */ \
            _Pragma("unroll") \
            for (int _m = 0; _m < 8; ++_m) { \
                float _xc = rl((cx), _w * 8 + _m); \
                STEP8(_xc); \
            } \
        } \
    } \
} while (0)

__global__ void __launch_bounds__(64, 1)
lif_chain_g(const float* __restrict__ x, const float* __restrict__ th,
            const float* __restrict__ HI, const float* __restrict__ LO,
            const float* __restrict__ PK, float* __restrict__ seb2)
{
    const int b = blockIdx.x;
    const int lane = threadIdx.x;
    const int l16 = lane & 15;
    const float* xb  = x  + (size_t)b * NT;
    const float* HIb = HI + (size_t)b * NG64 * 16;
    const float* LOb = LO + (size_t)b * NG64 * 16;
    const float* PKb = PK + (size_t)b * NG64 * 16;
    float* se2 = seb2 + (size_t)b * NG64;

    const float th0 = th[0], th1 = th[1], th2 = th[2], th3 = th[3];
    const float th4 = th[4], th5 = th[5], th6 = th[6], th7 = th[7];

    float s = 0.0f, keep = 0.0f;
    // prologue: pair 0 (groups 0,1)
    float cHa = HIb[l16],      cLa = LOb[l16],      cKa = PKb[l16];
    float cHb = HIb[16 + l16], cLb = LOb[16 + l16], cKb = PKb[16 + l16];
    float cxa = xb[lane], cxb = xb[64 + lane];

    for (int sg = 0; sg < 4; ++sg) {
        for (int gp = 0; gp < 32; ++gp) {
            const int gg = sg * 64 + gp * 2;
            int gn = gg + 2; if (gn > NG64 - 2) gn = NG64 - 2;
            // prefetch next pair (distance = 1 full pair body)
            float nHa = HIb[(size_t)gn * 16 + l16];
            float nLa = LOb[(size_t)gn * 16 + l16];
            float nKa = PKb[(size_t)gn * 16 + l16];
            float nHb = HIb[(size_t)(gn + 1) * 16 + l16];
            float nLb = LOb[(size_t)(gn + 1) * 16 + l16];
            float nKb = PKb[(size_t)(gn + 1) * 16 + l16];
            float nxa = xb[(size_t)gn * 64 + lane];
            float nxb = xb[(size_t)(gn + 1) * 64 + lane];

            PROCESS(cHa, cLa, cKa, cxa, gg);
            PROCESS(cHb, cLb, cKb, cxb, gg + 1);

            cHa = nHa; cLa = nLa; cKa = nKa; cxa = nxa;
            cHb = nHb; cLb = nLb; cKb = nKb; cxb = nxb;
        }
        se2[sg * 64 + lane] = keep;   // coalesced, 1 store / 64 groups
    }
}

// ---- replay: thread per (b, group, window); exact window entries ----
__global__ void __launch_bounds__(256)
lif_replay(const float* __restrict__ x, const float* __restrict__ th,
           const float* __restrict__ seb2, float* __restrict__ s_ent)
{
    int idx = blockIdx.x * 256 + threadIdx.x;   // b*2048 + gg*8 + w
    if (idx >= NB * NG64 * 8) return;
    int b = idx >> 11;
    int r = idx & 2047;
    int gg = r >> 3;
    int w = r & 7;

    const float th0 = th[0], th1 = th[1], th2 = th[2], th3 = th[3];
    const float th4 = th[4], th5 = th[5], th6 = th[6], th7 = th[7];

    float s = seb2[(size_t)b * NG64 + gg];
    const float* xg = x + (size_t)b * NT + gg * 64;
    const int nt = w * 8;
    for (int ti = 0; ti < nt; ++ti) {
        float xv = xg[ti];
        STEP8(xv);
    }
    s_ent[(size_t)b * NW2 + gg * 8 + w] = s;
}

// ---- output pass: fully parallel, bitwise-exact replay (unchanged) ----
__global__ void __launch_bounds__(128)
lif_out(const float* __restrict__ x, const float* __restrict__ th,
        const float* __restrict__ s_ent, float* __restrict__ out)
{
    const int j = threadIdx.x;             // 0..127
    const int i = blockIdx.x & (NS - 1);
    const int b = blockIdx.x >> 7;
    const int wl = j >> 3;                 // window within row (0..15)
    const int r  = j & 7;                  // position within window

    const float th0 = th[0], th1 = th[1], th2 = th[2], th3 = th[3];
    const float th4 = th[4], th5 = th[5], th6 = th[6], th7 = th[7];

    float s = s_ent[(size_t)b * NW2 + i * 16 + wl];
    const float* xrow = x + (size_t)b * NT + i * NH + (wl << 3);

    for (int m = 0; m < r; ++m) {          // replay to own t (<=7 steps)
        float xv = xrow[m];
        STEP8(xv);
    }
    float xv = xrow[r];

    float* o  = out + (((size_t)b * NS + i) * NK) * NH + j;
    float* sp = o + OUTN;
    float thr[NK];
#pragma unroll
    for (int k = 0; k < NK; ++k) thr[k] = th[k];
#pragma unroll
    for (int k = 0; k < NK; ++k) {
        s += xv;
        bool spike = s > thr[k];
        o[(size_t)k * NH]  = spike ? s : 0.0f;
        sp[(size_t)k * NH] = spike ? 1.0f : 0.0f;
        s = spike ? 0.0f : s;
    }
}

// ---- fallback if ws is tiny ----
__global__ void lif_mono(const float* __restrict__ x, const float* __restrict__ th,
                         float* __restrict__ out)
{
    int b = blockIdx.x * 64 + threadIdx.x;
    if (b >= NB) return;
    float thr[NK];
#pragma unroll
    for (int k = 0; k < NK; ++k) thr[k] = th[k];
    const float* xb = x + (size_t)b * NT;
    float s = 0.0f;
    for (int i = 0; i < NS; ++i)
        for (int j = 0; j < NH; ++j) {
            float xv = xb[i * NH + j];
#pragma unroll
            for (int k = 0; k < NK; ++k) {
                s += xv;
                bool spike = s > thr[k];
                size_t idx = (((size_t)b * NS + i) * NK + k) * NH + j;
                out[idx]        = spike ? s : 0.0f;
                out[OUTN + idx] = spike ? 1.0f : 0.0f;
                s = spike ? 0.0f : s;
            }
        }
}

extern "C" void kernel_launch(void* const* d_in, const int* in_sizes, int n_in,
                              void* d_out, int out_size, void* d_ws, size_t ws_size,
                              hipStream_t stream) {
    const float* x  = (const float*)d_in[0];   // (128,128,128) fp32
    const float* th = (const float*)d_in[1];   // (8,) fp32
    float* out = (float*)d_out;
    float* ws  = (float*)d_ws;

    if (ws_size >= (size_t)WS_TOT * sizeof(float)) {
        float* seb2  = ws + WS_SENT2;
        float* s_ent = ws + WS_SENT;
        float* HIb   = ws + WS_HI;
        float* LOb   = ws + WS_LO;
        float* PKb   = ws + WS_PK;
        int*   JTb   = (int*)(ws + WS_JT);

        lif_rec<<<dim3((NB * NG64 + 255) / 256), dim3(256), 0, stream>>>(x, th, HIb, LOb, JTb);
        lif_cont<<<dim3((NB * NG64 * 16 + 255) / 256), dim3(256), 0, stream>>>(x, th, JTb, PKb);
        lif_chain_g<<<dim3(NB), dim3(64), 0, stream>>>(x, th, HIb, LOb, PKb, seb2);
        lif_replay<<<dim3((NB * NG64 * 8 + 255) / 256), dim3(256), 0, stream>>>(x, th, seb2, s_ent);
        lif_out<<<dim3(NB * NS), dim3(128), 0, stream>>>(x, th, s_ent, out);
    } else {
        lif_mono<<<dim3(2), dim3(64), 0, stream>>>(x, th, out);
    }
}